// Round 1
// baseline (578.829 us; speedup 1.0000x reference)
//
#include <hip/hip_runtime.h>
#include <hip/hip_bf16.h>
#include <math.h>

#define N_NODES 50000
#define N_EDGES 800000
#define NEG_SLOPE 0.2f
#define EPS_DEN 1e-9f

constexpr int SCAN_BLK = 1024;
constexpr int NB_SCAN = (N_NODES + SCAN_BLK - 1) / SCAN_BLK; // 49

// ---------------- CSR build ----------------

__global__ void count_k(const int* __restrict__ dst, int* __restrict__ deg) {
    int e = blockIdx.x * 256 + threadIdx.x;
    if (e < N_EDGES) atomicAdd(&deg[dst[e]], 1);
}

__global__ void scan1_k(const int* __restrict__ deg, int* __restrict__ off,
                        int* __restrict__ bsum) {
    __shared__ int sh[256];
    int b = blockIdx.x, t = threadIdx.x;
    int base = b * SCAN_BLK + t * 4;
    int v[4]; int s = 0;
    #pragma unroll
    for (int i = 0; i < 4; ++i) {
        int idx = base + i;
        v[i] = (idx < N_NODES) ? deg[idx] : 0;
        s += v[i];
    }
    sh[t] = s; __syncthreads();
    for (int ofs = 1; ofs < 256; ofs <<= 1) {
        int x = 0;
        if (t >= ofs) x = sh[t - ofs];
        __syncthreads();
        sh[t] += x;
        __syncthreads();
    }
    int excl = sh[t] - s;
    if (t == 255) bsum[b] = sh[255];
    int run = excl;
    #pragma unroll
    for (int i = 0; i < 4; ++i) {
        int idx = base + i;
        if (idx < N_NODES) off[idx] = run;
        run += v[i];
    }
}

__global__ void scan2_k(int* __restrict__ bsum) {
    if (threadIdx.x == 0) {
        int run = 0;
        for (int i = 0; i < NB_SCAN; ++i) { int v = bsum[i]; bsum[i] = run; run += v; }
    }
}

__global__ void scan3_k(int* __restrict__ off, const int* __restrict__ bsum) {
    int i = blockIdx.x * 256 + threadIdx.x;
    if (i < N_NODES) off[i] += bsum[i >> 10];
    if (i == 0) off[N_NODES] = N_EDGES;
}

__global__ void scatter_k(const int* __restrict__ src, const int* __restrict__ dst,
                          int* __restrict__ cursor, int* __restrict__ csr) {
    int e = blockIdx.x * 256 + threadIdx.x;
    if (e < N_EDGES) {
        int p = atomicAdd(&cursor[dst[e]], 1);
        csr[p] = src[e];
    }
}

// ---------------- GEMM1: feat1 = h @ W1  (50000x256 @ 256x128) ----------------
// 128x128 tile / block of 256 threads, 8x8 microtile per thread.

__global__ void gemm1_k(const float* __restrict__ H, const float* __restrict__ W,
                        float* __restrict__ F) {
    __shared__ float hT[16][132];  // [k][row], padded
    __shared__ float ws[16][128];  // [k][col]
    int t = threadIdx.x;
    int tx = t & 15, ty = t >> 4;
    int rowBase = blockIdx.x * 128;
    float acc[8][8] = {};
    for (int k0 = 0; k0 < 256; k0 += 16) {
        // stage A (transposed): rows rowBase..+127, k k0..+15
        int r = t >> 2;
        int c4 = (t & 3) << 2;
        #pragma unroll
        for (int rr = 0; rr < 2; ++rr) {
            int row = r + rr * 64;
            float4 v = make_float4(0.f, 0.f, 0.f, 0.f);
            int grow = rowBase + row;
            if (grow < N_NODES)
                v = *(const float4*)&H[(size_t)grow * 256 + k0 + c4];
            hT[c4 + 0][row] = v.x; hT[c4 + 1][row] = v.y;
            hT[c4 + 2][row] = v.z; hT[c4 + 3][row] = v.w;
        }
        // stage W: k k0..+15, 128 cols
        int wk = t >> 5;            // 0..7
        int wj = (t & 31) << 2;     // 0..124
        #pragma unroll
        for (int kk = 0; kk < 2; ++kk) {
            int k = wk + kk * 8;
            *(float4*)&ws[k][wj] = *(const float4*)&W[(size_t)(k0 + k) * 128 + wj];
        }
        __syncthreads();
        #pragma unroll
        for (int k = 0; k < 16; ++k) {
            float a[8], b[8];
            *(float4*)&a[0] = *(const float4*)&hT[k][ty * 8];
            *(float4*)&a[4] = *(const float4*)&hT[k][ty * 8 + 4];
            *(float4*)&b[0] = *(const float4*)&ws[k][tx * 8];
            *(float4*)&b[4] = *(const float4*)&ws[k][tx * 8 + 4];
            #pragma unroll
            for (int i = 0; i < 8; ++i)
                #pragma unroll
                for (int j = 0; j < 8; ++j)
                    acc[i][j] += a[i] * b[j];
        }
        __syncthreads();
    }
    #pragma unroll
    for (int i = 0; i < 8; ++i) {
        int row = rowBase + ty * 8 + i;
        if (row < N_NODES) {
            *(float4*)&F[(size_t)row * 128 + tx * 8]     = *(float4*)&acc[i][0];
            *(float4*)&F[(size_t)row * 128 + tx * 8 + 4] = *(float4*)&acc[i][4];
        }
    }
}

// ---------------- el1/er1: per (node, head) dot over 32 dims ----------------

__global__ void elr1_k(const float* __restrict__ F, const float* __restrict__ al,
                       const float* __restrict__ ar, float* __restrict__ el,
                       float* __restrict__ er) {
    int i = blockIdx.x * 256 + threadIdx.x;
    if (i >= N_NODES * 4) return;
    int hh = i & 3;
    const float* f = &F[(size_t)(i >> 2) * 128 + hh * 32];
    float sl = 0.f, sr = 0.f;
    #pragma unroll
    for (int j = 0; j < 32; ++j) {
        float v = f[j];
        sl += v * al[hh * 32 + j];
        sr += v * ar[hh * 32 + j];
    }
    el[i] = sl; er[i] = sr;
}

// ---------------- agg1: layer-1 softmax-aggregate + bias + ELU + fused GEMM2 ----------------
// block = 128 threads (one node): t = h*32 + j

__global__ void agg1_k(const float* __restrict__ F, const float* __restrict__ el,
                       const float* __restrict__ er, const int* __restrict__ off,
                       const int* __restrict__ csr, const float* __restrict__ b1,
                       const float* __restrict__ W2, const float* __restrict__ al2,
                       const float* __restrict__ ar2, float* __restrict__ feat2,
                       float* __restrict__ el2, float* __restrict__ er2) {
    int n = blockIdx.x;
    int t = threadIdx.x;
    int hh = t >> 5;      // head 0..3
    int j = t & 31;
    int e0 = off[n], e1 = off[n + 1];
    float erh = er[n * 4 + hh];

    // pass A: per-head max (lane-parallel within each 32-lane group)
    float mx = -INFINITY;
    for (int e = e0 + j; e < e1; e += 32) {
        int s = csr[e];
        float x = el[s * 4 + hh] + erh;
        x = x > 0.f ? x : NEG_SLOPE * x;
        mx = fmaxf(mx, x);
    }
    #pragma unroll
    for (int m = 16; m >= 1; m >>= 1) mx = fmaxf(mx, __shfl_xor(mx, m, 64));

    // pass B: all lanes of each group walk all edges; unnormalized weighted sum
    float acc = 0.f, dsum = 0.f;
    for (int e = e0; e < e1; ++e) {
        int s = csr[e];
        float x = el[s * 4 + hh] + erh;
        x = x > 0.f ? x : NEG_SLOPE * x;
        float w = __expf(x - mx);
        dsum += w;
        acc += w * F[(size_t)s * 128 + t];
    }
    float o = acc / (dsum + EPS_DEN) + b1[t];
    o = o > 0.f ? o : expm1f(o);   // ELU

    // fused GEMM2 epilogue: feat2[n][j2] = sum_k h1row[k] * W2[k][j2]
    __shared__ float h1row[128];
    __shared__ float red[4][32];
    h1row[t] = o;
    __syncthreads();
    float part = 0.f;
    #pragma unroll
    for (int i = 0; i < 32; ++i) {
        int k = hh * 32 + i;
        part += h1row[k] * W2[(size_t)k * 32 + j];
    }
    red[hh][j] = part;
    __syncthreads();
    if (t < 32) {
        float f2 = red[0][j] + red[1][j] + red[2][j] + red[3][j];
        feat2[(size_t)n * 32 + j] = f2;
        float sl = f2 * al2[j];
        float sr = f2 * ar2[j];
        #pragma unroll
        for (int m = 16; m >= 1; m >>= 1) {
            sl += __shfl_xor(sl, m, 64);
            sr += __shfl_xor(sr, m, 64);
        }
        if (j == 0) { el2[n] = sl; er2[n] = sr; }
    }
}

// ---------------- agg2: layer-2 softmax-aggregate -> output ----------------
// block = 64 threads (one wave) per node: p = t>>5 (edge slot), j = t&31 (dim)

__global__ void agg2_k(const float* __restrict__ F2, const float* __restrict__ el2,
                       const float* __restrict__ er2, const int* __restrict__ off,
                       const int* __restrict__ csr, const float* __restrict__ b2,
                       float* __restrict__ out) {
    int n = blockIdx.x;
    int t = threadIdx.x;
    int p = t >> 5, j = t & 31;
    int e0 = off[n], e1 = off[n + 1];
    float ern = er2[n];

    float mx = -INFINITY;
    for (int e = e0 + t; e < e1; e += 64) {
        float x = el2[csr[e]] + ern;
        x = x > 0.f ? x : NEG_SLOPE * x;
        mx = fmaxf(mx, x);
    }
    #pragma unroll
    for (int m = 32; m >= 1; m >>= 1) mx = fmaxf(mx, __shfl_xor(mx, m, 64));

    float acc = 0.f, dsum = 0.f;
    for (int e = e0 + p; e < e1; e += 2) {
        int s = csr[e];
        float x = el2[s] + ern;
        x = x > 0.f ? x : NEG_SLOPE * x;
        float w = __expf(x - mx);
        dsum += w;
        acc += w * F2[(size_t)s * 32 + j];
    }
    dsum += __shfl_xor(dsum, 32, 64);
    acc  += __shfl_xor(acc, 32, 64);
    if (t < 32) out[(size_t)n * 32 + j] = acc / (dsum + EPS_DEN) + b2[j];
}

// ---------------- launch ----------------

extern "C" void kernel_launch(void* const* d_in, const int* in_sizes, int n_in,
                              void* d_out, int out_size, void* d_ws, size_t ws_size,
                              hipStream_t stream) {
    const float* h   = (const float*)d_in[0];
    const float* W1  = (const float*)d_in[1];
    const float* al1 = (const float*)d_in[2];
    const float* ar1 = (const float*)d_in[3];
    const float* b1  = (const float*)d_in[4];
    const float* W2  = (const float*)d_in[5];
    const float* al2 = (const float*)d_in[6];
    const float* ar2 = (const float*)d_in[7];
    const float* b2  = (const float*)d_in[8];
    const int* src   = (const int*)d_in[9];
    const int* dst   = (const int*)d_in[10];
    float* out = (float*)d_out;

    char* wsb = (char*)d_ws;
    size_t o = 0;
    auto alloc = [&](size_t bytes) {
        void* p = wsb + o;
        o += (bytes + 255) & ~(size_t)255;
        return p;
    };
    int* deg     = (int*)alloc((size_t)N_NODES * 4);
    int* off     = (int*)alloc((size_t)(N_NODES + 1) * 4);
    int* cursor  = (int*)alloc((size_t)N_NODES * 4);
    int* csr     = (int*)alloc((size_t)N_EDGES * 4);
    int* bsum    = (int*)alloc((size_t)NB_SCAN * 4);
    float* feat1 = (float*)alloc((size_t)N_NODES * 128 * 4);
    float* el1   = (float*)alloc((size_t)N_NODES * 4 * 4);
    float* er1   = (float*)alloc((size_t)N_NODES * 4 * 4);
    float* feat2 = (float*)alloc((size_t)N_NODES * 32 * 4);
    float* el2   = (float*)alloc((size_t)N_NODES * 4);
    float* er2   = (float*)alloc((size_t)N_NODES * 4);

    hipMemsetAsync(deg, 0, (size_t)N_NODES * 4, stream);
    count_k<<<(N_EDGES + 255) / 256, 256, 0, stream>>>(dst, deg);
    scan1_k<<<NB_SCAN, 256, 0, stream>>>(deg, off, bsum);
    scan2_k<<<1, 64, 0, stream>>>(bsum);
    scan3_k<<<(N_NODES + 255) / 256, 256, 0, stream>>>(off, bsum);
    hipMemcpyAsync(cursor, off, (size_t)N_NODES * 4, hipMemcpyDeviceToDevice, stream);
    scatter_k<<<(N_EDGES + 255) / 256, 256, 0, stream>>>(src, dst, cursor, csr);
    gemm1_k<<<(N_NODES + 127) / 128, 256, 0, stream>>>(h, W1, feat1);
    elr1_k<<<(N_NODES * 4 + 255) / 256, 256, 0, stream>>>(feat1, al1, ar1, el1, er1);
    agg1_k<<<N_NODES, 128, 0, stream>>>(feat1, el1, er1, off, csr, b1, W2, al2, ar2,
                                        feat2, el2, er2);
    agg2_k<<<N_NODES, 64, 0, stream>>>(feat2, el2, er2, off, csr, b2, out);
}

// Round 2
// 332.122 us; speedup vs baseline: 1.7428x; 1.7428x over previous
//
#include <hip/hip_runtime.h>
#include <hip/hip_bf16.h>
#include <math.h>

#define N_NODES 50000
#define N_EDGES 800000
#define NEG_SLOPE 0.2f
#define EPS_DEN 1e-9f

constexpr int SCAN_BLK = 1024;
constexpr int NB_SCAN = (N_NODES + SCAN_BLK - 1) / SCAN_BLK; // 49

// ---------------- CSR build ----------------

__global__ void count_k(const int* __restrict__ dst, int* __restrict__ deg) {
    int e = blockIdx.x * 256 + threadIdx.x;
    if (e < N_EDGES) atomicAdd(&deg[dst[e]], 1);
}

__global__ void scan1_k(const int* __restrict__ deg, int* __restrict__ off,
                        int* __restrict__ bsum) {
    __shared__ int sh[256];
    int b = blockIdx.x, t = threadIdx.x;
    int base = b * SCAN_BLK + t * 4;
    int v[4]; int s = 0;
    #pragma unroll
    for (int i = 0; i < 4; ++i) {
        int idx = base + i;
        v[i] = (idx < N_NODES) ? deg[idx] : 0;
        s += v[i];
    }
    sh[t] = s; __syncthreads();
    for (int ofs = 1; ofs < 256; ofs <<= 1) {
        int x = 0;
        if (t >= ofs) x = sh[t - ofs];
        __syncthreads();
        sh[t] += x;
        __syncthreads();
    }
    int excl = sh[t] - s;
    if (t == 255) bsum[b] = sh[255];
    int run = excl;
    #pragma unroll
    for (int i = 0; i < 4; ++i) {
        int idx = base + i;
        if (idx < N_NODES) off[idx] = run;
        run += v[i];
    }
}

__global__ void scan2_k(int* __restrict__ bsum) {
    if (threadIdx.x == 0) {
        int run = 0;
        for (int i = 0; i < NB_SCAN; ++i) { int v = bsum[i]; bsum[i] = run; run += v; }
    }
}

__global__ void scan3_k(int* __restrict__ off, const int* __restrict__ bsum) {
    int i = blockIdx.x * 256 + threadIdx.x;
    if (i < N_NODES) off[i] += bsum[i >> 10];
    if (i == 0) off[N_NODES] = N_EDGES;
}

__global__ void scatter_k(const int* __restrict__ src, const int* __restrict__ dst,
                          int* __restrict__ cursor, int* __restrict__ csr) {
    int e = blockIdx.x * 256 + threadIdx.x;
    if (e < N_EDGES) {
        int p = atomicAdd(&cursor[dst[e]], 1);
        csr[p] = src[e];
    }
}

// ---------------- GEMM1: feat1 = h @ W1  (50000x256 @ 256x128) ----------------
// 64x128 tile / 256 threads, 4x8 microtile, register-prefetch of next K-tile.
// Col microtile interleaved (tx*4 and 64+tx*4) to spread LDS banks.

__global__ __launch_bounds__(256) void gemm1_k(const float* __restrict__ H,
                                               const float* __restrict__ W,
                                               float* __restrict__ F) {
    __shared__ float hT[16][68];   // [k][row], padded
    __shared__ float ws[16][128];  // [k][col]
    int t = threadIdx.x;
    int tx = t & 15, ty = t >> 4;          // tx: col group, ty: row group
    int rowBase = blockIdx.x * 64;
    float acc[4][8] = {};

    // staging indices
    int sr  = t >> 2;          // 0..63 row for A staging
    int sc4 = (t & 3) << 2;    // 0,4,8,12 k offset for A staging
    int wk  = t >> 5;          // 0..7
    int wj  = (t & 31) << 2;   // 0..124

    // prefetch k0 = 0
    float4 va = make_float4(0.f, 0.f, 0.f, 0.f);
    {
        int grow = rowBase + sr;
        if (grow < N_NODES) va = *(const float4*)&H[(size_t)grow * 256 + sc4];
    }
    float4 vw0 = *(const float4*)&W[(size_t)wk * 128 + wj];
    float4 vw1 = *(const float4*)&W[(size_t)(wk + 8) * 128 + wj];

    for (int k0 = 0; k0 < 256; k0 += 16) {
        __syncthreads();
        hT[sc4 + 0][sr] = va.x; hT[sc4 + 1][sr] = va.y;
        hT[sc4 + 2][sr] = va.z; hT[sc4 + 3][sr] = va.w;
        *(float4*)&ws[wk][wj]     = vw0;
        *(float4*)&ws[wk + 8][wj] = vw1;
        __syncthreads();

        if (k0 + 16 < 256) {
            int k1 = k0 + 16;
            va = make_float4(0.f, 0.f, 0.f, 0.f);
            int grow = rowBase + sr;
            if (grow < N_NODES) va = *(const float4*)&H[(size_t)grow * 256 + k1 + sc4];
            vw0 = *(const float4*)&W[(size_t)(k1 + wk) * 128 + wj];
            vw1 = *(const float4*)&W[(size_t)(k1 + wk + 8) * 128 + wj];
        }

        #pragma unroll
        for (int k = 0; k < 16; ++k) {
            float4 a4 = *(const float4*)&hT[k][ty * 4];
            float4 b0 = *(const float4*)&ws[k][tx * 4];
            float4 b1 = *(const float4*)&ws[k][64 + tx * 4];
            float a[4] = {a4.x, a4.y, a4.z, a4.w};
            float b[8] = {b0.x, b0.y, b0.z, b0.w, b1.x, b1.y, b1.z, b1.w};
            #pragma unroll
            for (int i = 0; i < 4; ++i)
                #pragma unroll
                for (int j = 0; j < 8; ++j)
                    acc[i][j] = fmaf(a[i], b[j], acc[i][j]);
        }
    }

    #pragma unroll
    for (int i = 0; i < 4; ++i) {
        int row = rowBase + ty * 4 + i;
        if (row < N_NODES) {
            *(float4*)&F[(size_t)row * 128 + tx * 4] =
                make_float4(acc[i][0], acc[i][1], acc[i][2], acc[i][3]);
            *(float4*)&F[(size_t)row * 128 + 64 + tx * 4] =
                make_float4(acc[i][4], acc[i][5], acc[i][6], acc[i][7]);
        }
    }
}

// ---------------- el1/er1: per (node, head) dot over 32 dims ----------------

__global__ void elr1_k(const float* __restrict__ F, const float* __restrict__ al,
                       const float* __restrict__ ar, float* __restrict__ el,
                       float* __restrict__ er) {
    int i = blockIdx.x * 256 + threadIdx.x;
    if (i >= N_NODES * 4) return;
    int hh = i & 3;
    const float* f = &F[(size_t)(i >> 2) * 128 + hh * 32];
    float sl = 0.f, sr = 0.f;
    #pragma unroll
    for (int j = 0; j < 32; ++j) {
        float v = f[j];
        sl += v * al[hh * 32 + j];
        sr += v * ar[hh * 32 + j];
    }
    el[i] = sl; er[i] = sr;
}

// ---------------- agg1: layer-1 softmax-aggregate + bias + ELU + fused GEMM2 ----------------
// block = 128 threads (one node): t = h*32 + j

__global__ void agg1_k(const float* __restrict__ F, const float* __restrict__ el,
                       const float* __restrict__ er, const int* __restrict__ off,
                       const int* __restrict__ csr, const float* __restrict__ b1,
                       const float* __restrict__ W2, const float* __restrict__ al2,
                       const float* __restrict__ ar2, float* __restrict__ feat2,
                       float* __restrict__ el2, float* __restrict__ er2) {
    int n = blockIdx.x;
    int t = threadIdx.x;
    int hh = t >> 5;      // head 0..3
    int j = t & 31;
    int e0 = off[n], e1 = off[n + 1];
    float erh = er[n * 4 + hh];

    // pass A: per-head max (lane-parallel within each 32-lane group)
    float mx = -INFINITY;
    for (int e = e0 + j; e < e1; e += 32) {
        int s = csr[e];
        float x = el[s * 4 + hh] + erh;
        x = x > 0.f ? x : NEG_SLOPE * x;
        mx = fmaxf(mx, x);
    }
    #pragma unroll
    for (int m = 16; m >= 1; m >>= 1) mx = fmaxf(mx, __shfl_xor(mx, m, 64));

    // pass B: all lanes of each group walk all edges; unnormalized weighted sum
    float acc = 0.f, dsum = 0.f;
    for (int e = e0; e < e1; ++e) {
        int s = csr[e];
        float x = el[s * 4 + hh] + erh;
        x = x > 0.f ? x : NEG_SLOPE * x;
        float w = __expf(x - mx);
        dsum += w;
        acc += w * F[(size_t)s * 128 + t];
    }
    float o = acc / (dsum + EPS_DEN) + b1[t];
    o = o > 0.f ? o : expm1f(o);   // ELU

    // fused GEMM2 epilogue: feat2[n][j2] = sum_k h1row[k] * W2[k][j2]
    __shared__ float h1row[128];
    __shared__ float red[4][32];
    h1row[t] = o;
    __syncthreads();
    float part = 0.f;
    #pragma unroll
    for (int i = 0; i < 32; ++i) {
        int k = hh * 32 + i;
        part += h1row[k] * W2[(size_t)k * 32 + j];
    }
    red[hh][j] = part;
    __syncthreads();
    if (t < 32) {
        float f2 = red[0][j] + red[1][j] + red[2][j] + red[3][j];
        feat2[(size_t)n * 32 + j] = f2;
        float sl = f2 * al2[j];
        float sr = f2 * ar2[j];
        #pragma unroll
        for (int m = 16; m >= 1; m >>= 1) {
            sl += __shfl_xor(sl, m, 64);
            sr += __shfl_xor(sr, m, 64);
        }
        if (j == 0) { el2[n] = sl; er2[n] = sr; }
    }
}

// ---------------- agg2: layer-2 softmax-aggregate -> output ----------------
// block = 64 threads (one wave) per node: p = t>>5 (edge slot), j = t&31 (dim)

__global__ void agg2_k(const float* __restrict__ F2, const float* __restrict__ el2,
                       const float* __restrict__ er2, const int* __restrict__ off,
                       const int* __restrict__ csr, const float* __restrict__ b2,
                       float* __restrict__ out) {
    int n = blockIdx.x;
    int t = threadIdx.x;
    int p = t >> 5, j = t & 31;
    int e0 = off[n], e1 = off[n + 1];
    float ern = er2[n];

    float mx = -INFINITY;
    for (int e = e0 + t; e < e1; e += 64) {
        float x = el2[csr[e]] + ern;
        x = x > 0.f ? x : NEG_SLOPE * x;
        mx = fmaxf(mx, x);
    }
    #pragma unroll
    for (int m = 32; m >= 1; m >>= 1) mx = fmaxf(mx, __shfl_xor(mx, m, 64));

    float acc = 0.f, dsum = 0.f;
    for (int e = e0 + p; e < e1; e += 2) {
        int s = csr[e];
        float x = el2[s] + ern;
        x = x > 0.f ? x : NEG_SLOPE * x;
        float w = __expf(x - mx);
        dsum += w;
        acc += w * F2[(size_t)s * 32 + j];
    }
    dsum += __shfl_xor(dsum, 32, 64);
    acc  += __shfl_xor(acc, 32, 64);
    if (t < 32) out[(size_t)n * 32 + j] = acc / (dsum + EPS_DEN) + b2[j];
}

// ---------------- launch ----------------

extern "C" void kernel_launch(void* const* d_in, const int* in_sizes, int n_in,
                              void* d_out, int out_size, void* d_ws, size_t ws_size,
                              hipStream_t stream) {
    const float* h   = (const float*)d_in[0];
    const float* W1  = (const float*)d_in[1];
    const float* al1 = (const float*)d_in[2];
    const float* ar1 = (const float*)d_in[3];
    const float* b1  = (const float*)d_in[4];
    const float* W2  = (const float*)d_in[5];
    const float* al2 = (const float*)d_in[6];
    const float* ar2 = (const float*)d_in[7];
    const float* b2  = (const float*)d_in[8];
    const int* src   = (const int*)d_in[9];
    const int* dst   = (const int*)d_in[10];
    float* out = (float*)d_out;

    char* wsb = (char*)d_ws;
    size_t o = 0;
    auto alloc = [&](size_t bytes) {
        void* p = wsb + o;
        o += (bytes + 255) & ~(size_t)255;
        return p;
    };
    int* deg     = (int*)alloc((size_t)N_NODES * 4);
    int* off     = (int*)alloc((size_t)(N_NODES + 1) * 4);
    int* cursor  = (int*)alloc((size_t)N_NODES * 4);
    int* csr     = (int*)alloc((size_t)N_EDGES * 4);
    int* bsum    = (int*)alloc((size_t)NB_SCAN * 4);
    float* feat1 = (float*)alloc((size_t)N_NODES * 128 * 4);
    float* el1   = (float*)alloc((size_t)N_NODES * 4 * 4);
    float* er1   = (float*)alloc((size_t)N_NODES * 4 * 4);
    float* feat2 = (float*)alloc((size_t)N_NODES * 32 * 4);
    float* el2   = (float*)alloc((size_t)N_NODES * 4);
    float* er2   = (float*)alloc((size_t)N_NODES * 4);

    hipMemsetAsync(deg, 0, (size_t)N_NODES * 4, stream);
    count_k<<<(N_EDGES + 255) / 256, 256, 0, stream>>>(dst, deg);
    scan1_k<<<NB_SCAN, 256, 0, stream>>>(deg, off, bsum);
    scan2_k<<<1, 64, 0, stream>>>(bsum);
    scan3_k<<<(N_NODES + 255) / 256, 256, 0, stream>>>(off, bsum);
    hipMemcpyAsync(cursor, off, (size_t)N_NODES * 4, hipMemcpyDeviceToDevice, stream);
    scatter_k<<<(N_EDGES + 255) / 256, 256, 0, stream>>>(src, dst, cursor, csr);
    gemm1_k<<<(N_NODES + 63) / 64, 256, 0, stream>>>(h, W1, feat1);
    elr1_k<<<(N_NODES * 4 + 255) / 256, 256, 0, stream>>>(feat1, al1, ar1, el1, er1);
    agg1_k<<<N_NODES, 128, 0, stream>>>(feat1, el1, er1, off, csr, b1, W2, al2, ar2,
                                        feat2, el2, er2);
    agg2_k<<<N_NODES, 64, 0, stream>>>(feat2, el2, er2, off, csr, b2, out);
}

// Round 3
// 273.531 us; speedup vs baseline: 2.1161x; 1.2142x over previous
//
#include <hip/hip_runtime.h>
#include <hip/hip_bf16.h>
#include <math.h>

#define N_NODES 50000
#define N_EDGES 800000
#define NEG_SLOPE 0.2f
#define EPS_DEN 1e-9f

constexpr int SCAN_BLK = 1024;
constexpr int NB_SCAN = (N_NODES + SCAN_BLK - 1) / SCAN_BLK; // 49

// ---------------- CSR build ----------------

__global__ void count_k(const int* __restrict__ dst, int* __restrict__ deg) {
    int e = blockIdx.x * 256 + threadIdx.x;
    if (e < N_EDGES) atomicAdd(&deg[dst[e]], 1);
}

__global__ void scan1_k(const int* __restrict__ deg, int* __restrict__ off,
                        int* __restrict__ bsum) {
    __shared__ int sh[256];
    int b = blockIdx.x, t = threadIdx.x;
    int base = b * SCAN_BLK + t * 4;
    int v[4]; int s = 0;
    #pragma unroll
    for (int i = 0; i < 4; ++i) {
        int idx = base + i;
        v[i] = (idx < N_NODES) ? deg[idx] : 0;
        s += v[i];
    }
    sh[t] = s; __syncthreads();
    for (int ofs = 1; ofs < 256; ofs <<= 1) {
        int x = 0;
        if (t >= ofs) x = sh[t - ofs];
        __syncthreads();
        sh[t] += x;
        __syncthreads();
    }
    int excl = sh[t] - s;
    if (t == 255) bsum[b] = sh[255];
    int run = excl;
    #pragma unroll
    for (int i = 0; i < 4; ++i) {
        int idx = base + i;
        if (idx < N_NODES) off[idx] = run;
        run += v[i];
    }
}

__global__ void scan2_k(int* __restrict__ bsum) {
    if (threadIdx.x == 0) {
        int run = 0;
        for (int i = 0; i < NB_SCAN; ++i) { int v = bsum[i]; bsum[i] = run; run += v; }
    }
}

__global__ void scan3_k(int* __restrict__ off, const int* __restrict__ bsum) {
    int i = blockIdx.x * 256 + threadIdx.x;
    if (i < N_NODES) off[i] += bsum[i >> 10];
    if (i == 0) off[N_NODES] = N_EDGES;
}

// scatter + layer-1 edge weights (runs after elr1): w1[p][h] = exp(leaky(el1[s][h]+er1[d][h]))
__global__ void scatter_k(const int* __restrict__ src, const int* __restrict__ dst,
                          int* __restrict__ cursor, int* __restrict__ csr,
                          int* __restrict__ perm,
                          const float* __restrict__ el1, const float* __restrict__ er1,
                          float* __restrict__ wb1) {
    int e = blockIdx.x * 256 + threadIdx.x;
    if (e >= N_EDGES) return;
    int s = src[e], d = dst[e];
    int p = atomicAdd(&cursor[d], 1);
    csr[p] = s;
    perm[e] = p;
    float4 a = *(const float4*)&el1[(size_t)s * 4];
    float4 b = *(const float4*)&er1[(size_t)d * 4];
    float4 x = make_float4(a.x + b.x, a.y + b.y, a.z + b.z, a.w + b.w);
    x.x = x.x > 0.f ? x.x : NEG_SLOPE * x.x;
    x.y = x.y > 0.f ? x.y : NEG_SLOPE * x.y;
    x.z = x.z > 0.f ? x.z : NEG_SLOPE * x.z;
    x.w = x.w > 0.f ? x.w : NEG_SLOPE * x.w;
    float4 w = make_float4(__expf(x.x), __expf(x.y), __expf(x.z), __expf(x.w));
    *(float4*)&wb1[(size_t)p * 4] = w;
}

// ---------------- GEMM1: feat1 = h @ W1  (50000x256 @ 256x128) ----------------

__global__ __launch_bounds__(256) void gemm1_k(const float* __restrict__ H,
                                               const float* __restrict__ W,
                                               float* __restrict__ F) {
    __shared__ float hT[16][68];   // [k][row], padded
    __shared__ float ws[16][128];  // [k][col]
    int t = threadIdx.x;
    int tx = t & 15, ty = t >> 4;
    int rowBase = blockIdx.x * 64;
    float acc[4][8] = {};

    int sr  = t >> 2;
    int sc4 = (t & 3) << 2;
    int wk  = t >> 5;
    int wj  = (t & 31) << 2;

    float4 va = make_float4(0.f, 0.f, 0.f, 0.f);
    {
        int grow = rowBase + sr;
        if (grow < N_NODES) va = *(const float4*)&H[(size_t)grow * 256 + sc4];
    }
    float4 vw0 = *(const float4*)&W[(size_t)wk * 128 + wj];
    float4 vw1 = *(const float4*)&W[(size_t)(wk + 8) * 128 + wj];

    for (int k0 = 0; k0 < 256; k0 += 16) {
        __syncthreads();
        hT[sc4 + 0][sr] = va.x; hT[sc4 + 1][sr] = va.y;
        hT[sc4 + 2][sr] = va.z; hT[sc4 + 3][sr] = va.w;
        *(float4*)&ws[wk][wj]     = vw0;
        *(float4*)&ws[wk + 8][wj] = vw1;
        __syncthreads();

        if (k0 + 16 < 256) {
            int k1 = k0 + 16;
            va = make_float4(0.f, 0.f, 0.f, 0.f);
            int grow = rowBase + sr;
            if (grow < N_NODES) va = *(const float4*)&H[(size_t)grow * 256 + k1 + sc4];
            vw0 = *(const float4*)&W[(size_t)(k1 + wk) * 128 + wj];
            vw1 = *(const float4*)&W[(size_t)(k1 + wk + 8) * 128 + wj];
        }

        #pragma unroll
        for (int k = 0; k < 16; ++k) {
            float4 a4 = *(const float4*)&hT[k][ty * 4];
            float4 b0 = *(const float4*)&ws[k][tx * 4];
            float4 b1 = *(const float4*)&ws[k][64 + tx * 4];
            float a[4] = {a4.x, a4.y, a4.z, a4.w};
            float b[8] = {b0.x, b0.y, b0.z, b0.w, b1.x, b1.y, b1.z, b1.w};
            #pragma unroll
            for (int i = 0; i < 4; ++i)
                #pragma unroll
                for (int j = 0; j < 8; ++j)
                    acc[i][j] = fmaf(a[i], b[j], acc[i][j]);
        }
    }

    #pragma unroll
    for (int i = 0; i < 4; ++i) {
        int row = rowBase + ty * 4 + i;
        if (row < N_NODES) {
            *(float4*)&F[(size_t)row * 128 + tx * 4] =
                make_float4(acc[i][0], acc[i][1], acc[i][2], acc[i][3]);
            *(float4*)&F[(size_t)row * 128 + 64 + tx * 4] =
                make_float4(acc[i][4], acc[i][5], acc[i][6], acc[i][7]);
        }
    }
}

// ---------------- el1/er1 ----------------

__global__ void elr1_k(const float* __restrict__ F, const float* __restrict__ al,
                       const float* __restrict__ ar, float* __restrict__ el,
                       float* __restrict__ er) {
    int i = blockIdx.x * 256 + threadIdx.x;
    if (i >= N_NODES * 4) return;
    int hh = i & 3;
    const float* f = &F[(size_t)(i >> 2) * 128 + hh * 32];
    float sl = 0.f, sr = 0.f;
    #pragma unroll
    for (int q = 0; q < 8; ++q) {
        float4 v = *(const float4*)&f[q * 4];
        float4 A = *(const float4*)&al[hh * 32 + q * 4];
        float4 B = *(const float4*)&ar[hh * 32 + q * 4];
        sl += v.x * A.x + v.y * A.y + v.z * A.z + v.w * A.w;
        sr += v.x * B.x + v.y * B.y + v.z * B.z + v.w * B.w;
    }
    el[i] = sl; er[i] = sr;
}

// ---------------- agg1: wave-per-node aggregate + bias + ELU + fused GEMM2 ----------------
// wave = 64 lanes: half = edge parity, l = lane in half (dims 4l..4l+3, head l>>3)

__global__ __launch_bounds__(256) void agg1_k(const float* __restrict__ F,
                                              const int* __restrict__ off,
                                              const int* __restrict__ csr,
                                              const float* __restrict__ wb1,
                                              const float* __restrict__ b1,
                                              const float* __restrict__ W2,
                                              const float* __restrict__ al2,
                                              const float* __restrict__ ar2,
                                              float* __restrict__ feat2,
                                              float* __restrict__ el2,
                                              float* __restrict__ er2) {
    __shared__ float h1row[4][128];
    int wid = threadIdx.x >> 6;
    int n = blockIdx.x * 4 + wid;
    if (n >= N_NODES) return;
    int t = threadIdx.x & 63;
    int half = t >> 5;
    int l = t & 31;
    int hh = l >> 3;
    int e0 = off[n], e1 = off[n + 1];

    float4 acc = make_float4(0.f, 0.f, 0.f, 0.f);
    float dsum = 0.f;
    for (int e = e0 + half; e < e1; e += 2) {
        int s = csr[e];
        float w = wb1[(size_t)e * 4 + hh];
        float4 f = *(const float4*)&F[(size_t)s * 128 + l * 4];
        acc.x = fmaf(w, f.x, acc.x);
        acc.y = fmaf(w, f.y, acc.y);
        acc.z = fmaf(w, f.z, acc.z);
        acc.w = fmaf(w, f.w, acc.w);
        dsum += w;
    }
    acc.x += __shfl_xor(acc.x, 32, 64);
    acc.y += __shfl_xor(acc.y, 32, 64);
    acc.z += __shfl_xor(acc.z, 32, 64);
    acc.w += __shfl_xor(acc.w, 32, 64);
    dsum  += __shfl_xor(dsum, 32, 64);

    float inv = 1.f / (dsum + EPS_DEN);
    float4 bv = *(const float4*)&b1[l * 4];
    float4 o;
    o.x = fmaf(acc.x, inv, bv.x);
    o.y = fmaf(acc.y, inv, bv.y);
    o.z = fmaf(acc.z, inv, bv.z);
    o.w = fmaf(acc.w, inv, bv.w);
    o.x = o.x > 0.f ? o.x : expm1f(o.x);
    o.y = o.y > 0.f ? o.y : expm1f(o.y);
    o.z = o.z > 0.f ? o.z : expm1f(o.z);
    o.w = o.w > 0.f ? o.w : expm1f(o.w);

    if (half == 0) *(float4*)&h1row[wid][l * 4] = o;
    // wave-coherent LDS RAW; compiler inserts lgkmcnt wait

    float part = 0.f;
    int kb = half << 6;
    #pragma unroll 8
    for (int k = 0; k < 64; ++k)
        part = fmaf(h1row[wid][kb + k], W2[(size_t)(kb + k) * 32 + l], part);
    part += __shfl_xor(part, 32, 64);

    if (half == 0) {
        feat2[(size_t)n * 32 + l] = part;
        float sl = part * al2[l];
        float sr = part * ar2[l];
        #pragma unroll
        for (int m = 16; m >= 1; m >>= 1) {
            sl += __shfl_xor(sl, m, 64);
            sr += __shfl_xor(sr, m, 64);
        }
        if (l == 0) { el2[n] = sl; er2[n] = sr; }
    }
}

// ---------------- layer-2 edge weights ----------------

__global__ void w2_k(const int* __restrict__ src, const int* __restrict__ dst,
                     const int* __restrict__ perm, const float* __restrict__ el2,
                     const float* __restrict__ er2, float* __restrict__ w2buf) {
    int e = blockIdx.x * 256 + threadIdx.x;
    if (e >= N_EDGES) return;
    float x = el2[src[e]] + er2[dst[e]];
    x = x > 0.f ? x : NEG_SLOPE * x;
    w2buf[perm[e]] = __expf(x);
}

// ---------------- agg2: wave-per-node -> output ----------------
// 8 edge slots x 8 lanes (dims 4l..4l+3)

__global__ __launch_bounds__(256) void agg2_k(const float* __restrict__ F2,
                                              const int* __restrict__ off,
                                              const int* __restrict__ csr,
                                              const float* __restrict__ w2,
                                              const float* __restrict__ b2,
                                              float* __restrict__ out) {
    int wid = threadIdx.x >> 6;
    int n = blockIdx.x * 4 + wid;
    if (n >= N_NODES) return;
    int t = threadIdx.x & 63;
    int g = t >> 3, l = t & 7;
    int e0 = off[n], e1 = off[n + 1];

    float4 acc = make_float4(0.f, 0.f, 0.f, 0.f);
    float dsum = 0.f;
    for (int e = e0 + g; e < e1; e += 8) {
        int s = csr[e];
        float w = w2[e];
        float4 f = *(const float4*)&F2[(size_t)s * 32 + l * 4];
        acc.x = fmaf(w, f.x, acc.x);
        acc.y = fmaf(w, f.y, acc.y);
        acc.z = fmaf(w, f.z, acc.z);
        acc.w = fmaf(w, f.w, acc.w);
        dsum += w;
    }
    #pragma unroll
    for (int m = 8; m <= 32; m <<= 1) {
        acc.x += __shfl_xor(acc.x, m, 64);
        acc.y += __shfl_xor(acc.y, m, 64);
        acc.z += __shfl_xor(acc.z, m, 64);
        acc.w += __shfl_xor(acc.w, m, 64);
        dsum  += __shfl_xor(dsum, m, 64);
    }
    if (t < 8) {
        float inv = 1.f / (dsum + EPS_DEN);
        float4 bv = *(const float4*)&b2[t * 4];
        float4 r;
        r.x = fmaf(acc.x, inv, bv.x);
        r.y = fmaf(acc.y, inv, bv.y);
        r.z = fmaf(acc.z, inv, bv.z);
        r.w = fmaf(acc.w, inv, bv.w);
        *(float4*)&out[(size_t)n * 32 + t * 4] = r;
    }
}

// ---------------- launch ----------------

extern "C" void kernel_launch(void* const* d_in, const int* in_sizes, int n_in,
                              void* d_out, int out_size, void* d_ws, size_t ws_size,
                              hipStream_t stream) {
    const float* h   = (const float*)d_in[0];
    const float* W1  = (const float*)d_in[1];
    const float* al1 = (const float*)d_in[2];
    const float* ar1 = (const float*)d_in[3];
    const float* b1  = (const float*)d_in[4];
    const float* W2  = (const float*)d_in[5];
    const float* al2 = (const float*)d_in[6];
    const float* ar2 = (const float*)d_in[7];
    const float* b2  = (const float*)d_in[8];
    const int* src   = (const int*)d_in[9];
    const int* dst   = (const int*)d_in[10];
    float* out = (float*)d_out;

    char* wsb = (char*)d_ws;
    size_t o = 0;
    auto alloc = [&](size_t bytes) {
        void* p = wsb + o;
        o += (bytes + 255) & ~(size_t)255;
        return p;
    };
    int* deg     = (int*)alloc((size_t)N_NODES * 4);
    int* off     = (int*)alloc((size_t)(N_NODES + 1) * 4);
    int* cursor  = (int*)alloc((size_t)N_NODES * 4);
    int* csr     = (int*)alloc((size_t)N_EDGES * 4);
    int* perm    = (int*)alloc((size_t)N_EDGES * 4);
    int* bsum    = (int*)alloc((size_t)NB_SCAN * 4);
    float* feat1 = (float*)alloc((size_t)N_NODES * 128 * 4);
    float* el1   = (float*)alloc((size_t)N_NODES * 4 * 4);
    float* er1   = (float*)alloc((size_t)N_NODES * 4 * 4);
    float* wb1   = (float*)alloc((size_t)N_EDGES * 4 * 4);
    float* feat2 = (float*)alloc((size_t)N_NODES * 32 * 4);
    float* el2   = (float*)alloc((size_t)N_NODES * 4);
    float* er2   = (float*)alloc((size_t)N_NODES * 4);
    float* w2buf = wb1;  // reuse: wb1 dead after agg1, w2buf written after

    hipMemsetAsync(deg, 0, (size_t)N_NODES * 4, stream);
    count_k<<<(N_EDGES + 255) / 256, 256, 0, stream>>>(dst, deg);
    scan1_k<<<NB_SCAN, 256, 0, stream>>>(deg, off, bsum);
    scan2_k<<<1, 64, 0, stream>>>(bsum);
    scan3_k<<<(N_NODES + 255) / 256, 256, 0, stream>>>(off, bsum);
    hipMemcpyAsync(cursor, off, (size_t)N_NODES * 4, hipMemcpyDeviceToDevice, stream);
    gemm1_k<<<(N_NODES + 63) / 64, 256, 0, stream>>>(h, W1, feat1);
    elr1_k<<<(N_NODES * 4 + 255) / 256, 256, 0, stream>>>(feat1, al1, ar1, el1, er1);
    scatter_k<<<(N_EDGES + 255) / 256, 256, 0, stream>>>(src, dst, cursor, csr, perm,
                                                         el1, er1, wb1);
    agg1_k<<<(N_NODES + 3) / 4, 256, 0, stream>>>(feat1, off, csr, wb1, b1, W2,
                                                  al2, ar2, feat2, el2, er2);
    w2_k<<<(N_EDGES + 255) / 256, 256, 0, stream>>>(src, dst, perm, el2, er2, w2buf);
    agg2_k<<<(N_NODES + 3) / 4, 256, 0, stream>>>(feat2, off, csr, w2buf, b2, out);
}